// Round 1
// baseline (4181.022 us; speedup 1.0000x reference)
//
#include <hip/hip_runtime.h>
#include <hip/hip_bf16.h>

#define B_   32
#define T_   384
#define CF_  128
#define D_   512
#define H_   16
#define HD_  32
#define L_   16
#define HID_ 512
#define M_   (B_*T_)   // 12288

typedef __bf16 bf16x8 __attribute__((ext_vector_type(8)));
typedef float  f32x4  __attribute__((ext_vector_type(4)));

__device__ __forceinline__ float bf2f(unsigned short u){
    unsigned int x = ((unsigned int)u) << 16;
    return __builtin_bit_cast(float, x);
}
__device__ __forceinline__ unsigned short f2bf(float f){
    unsigned int u = __builtin_bit_cast(unsigned int, f);
    u += 0x7FFFu + ((u >> 16) & 1u);
    return (unsigned short)(u >> 16);
}

// ---------------------------------------------------------------------------
// Generic bf16 MFMA GEMM: C[M][N] = A[M][K] * Bt[N][K]^T  (Bt = B transposed)
// 128x128 tile, 256 threads (4 waves as 2x2 of 64x64), BK=32, double-buffered
// LDS with XOR slot swizzle (conflict-free ds_read_b128).
// EPI: 0=embed(+b+pe+lpe -> f32 x)  1=qkv scatter (bf16)
//      2=residual add (+bias -> f32 x +=)  3=relu(+bias -> bf16)
//      4=final (+bias -> f32 out, ld=128)
// ---------------------------------------------------------------------------
template<int EPI>
__global__ __launch_bounds__(256) void gemm_k(
    const unsigned short* __restrict__ A,
    const unsigned short* __restrict__ Bt,
    const float* __restrict__ aux0,   // bias
    const float* __restrict__ aux1,   // pe
    const float* __restrict__ aux2,   // learnable pe
    float* __restrict__ fout,
    unsigned short* __restrict__ bout,
    int K)
{
    __shared__ unsigned short lA[2][128*32];
    __shared__ unsigned short lB[2][128*32];

    const int tid  = threadIdx.x;
    const int lane = tid & 63;
    const int w    = tid >> 6;
    const int wm   = w >> 1, wn = w & 1;
    const int li   = lane & 15, ls = lane >> 4;
    const int m0   = blockIdx.x * 128;
    const int n0   = blockIdx.y * 128;
    const int nkt  = K >> 5;

    // staging: 512 chunks (128 rows x 4 slots of 8 bf16) per matrix, 2/thread
    const int e0 = tid, e1 = tid + 256;
    const int r0 = e0 >> 2, s0 = e0 & 3;
    const int r1 = e1 >> 2, s1 = e1 & 3;
    const int w0 = r0*32 + ((s0 ^ ((r0>>1)&3))*8);
    const int w1 = r1*32 + ((s1 ^ ((r1>>1)&3))*8);
    const unsigned short* Ar0 = A  + (size_t)(m0 + r0)*K + s0*8;
    const unsigned short* Ar1 = A  + (size_t)(m0 + r1)*K + s1*8;
    const unsigned short* Br0 = Bt + (size_t)(n0 + r0)*K + s0*8;
    const unsigned short* Br1 = Bt + (size_t)(n0 + r1)*K + s1*8;

    uint4 ra0 = *(const uint4*)(Ar0);
    uint4 ra1 = *(const uint4*)(Ar1);
    uint4 rb0 = *(const uint4*)(Br0);
    uint4 rb1 = *(const uint4*)(Br1);

    f32x4 acc[4][4];
    #pragma unroll
    for (int i=0;i<4;i++)
        #pragma unroll
        for (int j=0;j<4;j++) acc[i][j] = (f32x4){0.f,0.f,0.f,0.f};

    int cur = 0;
    for (int kt = 0; kt < nkt; ++kt){
        *(uint4*)&lA[cur][w0] = ra0;
        *(uint4*)&lA[cur][w1] = ra1;
        *(uint4*)&lB[cur][w0] = rb0;
        *(uint4*)&lB[cur][w1] = rb1;
        __syncthreads();
        if (kt + 1 < nkt){
            const int ko = (kt+1)*32;
            ra0 = *(const uint4*)(Ar0 + ko);
            ra1 = *(const uint4*)(Ar1 + ko);
            rb0 = *(const uint4*)(Br0 + ko);
            rb1 = *(const uint4*)(Br1 + ko);
        }
        bf16x8 af[4], bf[4];
        #pragma unroll
        for (int f=0; f<4; ++f){
            const int rA = wm*64 + f*16 + li;
            af[f] = *(const bf16x8*)&lA[cur][rA*32 + ((ls ^ ((rA>>1)&3))*8)];
            const int rB = wn*64 + f*16 + li;
            bf[f] = *(const bf16x8*)&lB[cur][rB*32 + ((ls ^ ((rB>>1)&3))*8)];
        }
        #pragma unroll
        for (int i=0;i<4;i++)
            #pragma unroll
            for (int j=0;j<4;j++)
                acc[i][j] = __builtin_amdgcn_mfma_f32_16x16x32_bf16(af[i], bf[j], acc[i][j], 0, 0, 0);
        cur ^= 1;
    }

    // epilogue: D layout col = lane&15, row = (lane>>4)*4 + t  (verified m89)
    #pragma unroll
    for (int i=0;i<4;i++){
        #pragma unroll
        for (int j=0;j<4;j++){
            #pragma unroll
            for (int t=0;t<4;t++){
                const int row = m0 + wm*64 + i*16 + ls*4 + t;
                const int col = n0 + wn*64 + j*16 + li;
                const float v = acc[i][j][t];
                if constexpr (EPI == 0){
                    const int tt = row % T_;
                    fout[row*D_ + col] = v + aux0[col] + aux1[tt*D_ + col] + aux2[tt*D_ + col];
                } else if constexpr (EPI == 1){
                    const int mat = col >> 9, nl = col & 511;
                    const int hh = nl >> 5, dd = nl & 31;
                    const int bb = row / T_, tt = row % T_;
                    bout[mat*(M_*D_) + (((bb*H_ + hh)*T_ + tt)*HD_) + dd] = f2bf(v);
                } else if constexpr (EPI == 2){
                    fout[row*D_ + col] += v + aux0[col];
                } else if constexpr (EPI == 3){
                    const float r = v + aux0[col];
                    bout[row*HID_ + col] = f2bf(r > 0.f ? r : 0.f);
                } else {
                    fout[row*CF_ + col] = v + aux0[col];
                }
            }
        }
    }
}

// ---------------------------------------------------------------------------
// LayerNorm: one wave per row of 512, out bf16
// ---------------------------------------------------------------------------
__global__ __launch_bounds__(256) void ln_k(const float* __restrict__ x,
                                            const float* __restrict__ g,
                                            const float* __restrict__ b,
                                            unsigned short* __restrict__ out)
{
    const int w = threadIdx.x >> 6, lane = threadIdx.x & 63;
    const int row = blockIdx.x*4 + w;
    const float* xr = x + (size_t)row*D_;
    const float4 a = *(const float4*)(xr + lane*8);
    const float4 c = *(const float4*)(xr + lane*8 + 4);
    float s  = a.x+a.y+a.z+a.w + c.x+c.y+c.z+c.w;
    float q2 = a.x*a.x+a.y*a.y+a.z*a.z+a.w*a.w + c.x*c.x+c.y*c.y+c.z*c.z+c.w*c.w;
    #pragma unroll
    for (int off=32; off; off>>=1){
        s  += __shfl_xor(s,  off);
        q2 += __shfl_xor(q2, off);
    }
    const float mean = s * (1.f/512.f);
    const float var  = q2 * (1.f/512.f) - mean*mean;
    const float rstd = rsqrtf(var + 1e-6f);
    const float4 gA = *(const float4*)(g + lane*8);
    const float4 gB = *(const float4*)(g + lane*8 + 4);
    const float4 bA = *(const float4*)(b + lane*8);
    const float4 bB = *(const float4*)(b + lane*8 + 4);
    alignas(16) unsigned short o8[8];
    o8[0] = f2bf((a.x-mean)*rstd*gA.x + bA.x);
    o8[1] = f2bf((a.y-mean)*rstd*gA.y + bA.y);
    o8[2] = f2bf((a.z-mean)*rstd*gA.z + bA.z);
    o8[3] = f2bf((a.w-mean)*rstd*gA.w + bA.w);
    o8[4] = f2bf((c.x-mean)*rstd*gB.x + bB.x);
    o8[5] = f2bf((c.y-mean)*rstd*gB.y + bB.y);
    o8[6] = f2bf((c.z-mean)*rstd*gB.z + bB.z);
    o8[7] = f2bf((c.w-mean)*rstd*gB.w + bB.w);
    *(uint4*)(out + (size_t)row*D_ + lane*8) = *(const uint4*)o8;
}

// ---------------------------------------------------------------------------
// Causal attention, scale = 1/sqrt(512). q,k,v: [BH][T][32] bf16.
// One block (4 waves) per (bh, 64-row t-tile). o: [B*T][512] bf16.
// ---------------------------------------------------------------------------
__global__ __launch_bounds__(256) void attn_k(const unsigned short* __restrict__ q,
                                              const unsigned short* __restrict__ k,
                                              const unsigned short* __restrict__ v,
                                              unsigned short* __restrict__ o)
{
    __shared__ unsigned short S[64][392];
    __shared__ unsigned short Vt[32][392];
    __shared__ float rowsum[64];

    const int bh  = blockIdx.y;
    const int t0  = blockIdx.x * 64;
    const int tid = threadIdx.x;
    const int lane = tid & 63, w = tid >> 6;
    const int li = lane & 15, ls = lane >> 4;
    const unsigned short* qb = q + (size_t)bh*(T_*HD_);
    const unsigned short* kb = k + (size_t)bh*(T_*HD_);
    const unsigned short* vb = v + (size_t)bh*(T_*HD_);

    // stage V transposed: Vt[d][s] = v[s][d] (ds-write conflict-free mapping)
    for (int idx = tid; idx < HD_*T_; idx += 256){
        const int d = idx / T_;
        const int s = idx - d*T_;
        Vt[d][s] = vb[s*HD_ + d];
    }

    const int trow0 = t0 + w*16;
    const bf16x8 qa = *(const bf16x8*)(qb + (trow0 + li)*HD_ + ls*8);
    const int nst16 = (trow0 >> 4) + 1;
    const float scale = 0.04419417382415922f;   // 1/sqrt(512)

    for (int st = 0; st < nst16; ++st){
        const bf16x8 kf = *(const bf16x8*)(kb + (st*16 + li)*HD_ + ls*8);
        f32x4 sa = (f32x4){0.f,0.f,0.f,0.f};
        sa = __builtin_amdgcn_mfma_f32_16x16x32_bf16(qa, kf, sa, 0, 0, 0);
        #pragma unroll
        for (int j=0;j<4;j++){
            const int tr = w*16 + ls*4 + j;
            S[tr][st*16 + li] = f2bf(sa[j] * scale);
        }
    }
    __syncthreads();

    // wave-parallel softmax: 4 lanes per row, unnormalized P in place
    {
        const int r  = w*16 + li;
        const int tg = t0 + r;
        const int ns = tg + 1;
        const int send = ((trow0 + 16 + 31) >> 5) << 5;
        float m = -1e30f;
        for (int s = ls; s < ns; s += 4) m = fmaxf(m, bf2f(S[r][s]));
        m = fmaxf(m, __shfl_xor(m, 16));
        m = fmaxf(m, __shfl_xor(m, 32));
        float sum = 0.f;
        for (int s = ls; s < ns; s += 4){
            const float e = __expf(bf2f(S[r][s]) - m);
            sum += e;
            S[r][s] = f2bf(e);
        }
        for (int s = (ns & ~3) + ls; s < send; s += 4)
            if (s >= ns) S[r][s] = 0;
        sum += __shfl_xor(sum, 16);
        sum += __shfl_xor(sum, 32);
        if (ls == 0) rowsum[r] = sum;
    }
    __syncthreads();

    // PV
    const int nst = (trow0 + 16 + 31) >> 5;
    f32x4 oa[2] = { (f32x4){0.f,0.f,0.f,0.f}, (f32x4){0.f,0.f,0.f,0.f} };
    for (int ss = 0; ss < nst; ++ss){
        const bf16x8 pf = *(const bf16x8*)&S[w*16 + li][ss*32 + ls*8];
        #pragma unroll
        for (int df=0; df<2; ++df){
            const bf16x8 vf = *(const bf16x8*)&Vt[df*16 + li][ss*32 + ls*8];
            oa[df] = __builtin_amdgcn_mfma_f32_16x16x32_bf16(pf, vf, oa[df], 0, 0, 0);
        }
    }
    const int bb = bh >> 4, hh = bh & 15;
    #pragma unroll
    for (int df=0; df<2; ++df){
        #pragma unroll
        for (int j=0;j<4;j++){
            const int tr = w*16 + ls*4 + j;
            const int tg = t0 + tr;
            const float val = oa[df][j] / rowsum[tr];
            o[(size_t)(bb*T_ + tg)*D_ + hh*HD_ + df*16 + li] = f2bf(val);
        }
    }
}

// ---------------------------------------------------------------------------
// Weight packing / casts / loss
// ---------------------------------------------------------------------------
__global__ void pack_qkv_k(const float* __restrict__ Wq, const float* __restrict__ Wk,
                           const float* __restrict__ Wv, unsigned short* __restrict__ dst)
{
    const int i = blockIdx.x*256 + threadIdx.x;        // 12,582,912 total
    const int l  = i / 786432;  const int r  = i - l*786432;
    const int mat= r / 262144;  const int r2 = r - mat*262144;
    const int n  = r2 >> 9;     const int kk = r2 & 511;
    const int hh = n >> 5, dd = n & 31;
    const float* src = (mat==0) ? Wq : (mat==1) ? Wk : Wv;
    dst[i] = f2bf(src[((size_t)(l*H_ + hh)*D_ + kk)*HD_ + dd]);
}

__global__ void pack_t_k(const float* __restrict__ src, unsigned short* __restrict__ dst,
                         int K, int N, int total)
{
    const int i = blockIdx.x*256 + threadIdx.x;
    if (i >= total) return;
    const int mn = K*N;
    const int l = i / mn;  const int r = i - l*mn;
    const int n = r / K;   const int kk = r - n*K;
    dst[i] = f2bf(src[(size_t)l*mn + (size_t)kk*N + n]);
}

__global__ void cast4_k(const float* __restrict__ src, unsigned short* __restrict__ dst, int total4)
{
    const int i = blockIdx.x*256 + threadIdx.x;
    if (i >= total4) return;
    const float4 vv = ((const float4*)src)[i];
    alignas(8) unsigned short t[4] = { f2bf(vv.x), f2bf(vv.y), f2bf(vv.z), f2bf(vv.w) };
    *(uint2*)(dst + (size_t)i*4) = *(const uint2*)t;
}

__global__ __launch_bounds__(256) void loss1_k(const float* __restrict__ logits,
                                               const float* __restrict__ tgt,
                                               float* __restrict__ part)
{
    float s = 0.f;
    for (int i = blockIdx.x*256 + threadIdx.x; i < M_*CF_; i += 256*1024){
        const float d = logits[i] - tgt[i];
        s += d*d;
    }
    #pragma unroll
    for (int off=32; off; off>>=1) s += __shfl_xor(s, off);
    __shared__ float ws4[4];
    if ((threadIdx.x & 63) == 0) ws4[threadIdx.x >> 6] = s;
    __syncthreads();
    if (threadIdx.x == 0) part[blockIdx.x] = ws4[0]+ws4[1]+ws4[2]+ws4[3];
}

__global__ __launch_bounds__(256) void loss2_k(const float* __restrict__ part,
                                               float* __restrict__ out)
{
    float s = 0.f;
    for (int i = threadIdx.x; i < 1024; i += 256) s += part[i];
    #pragma unroll
    for (int off=32; off; off>>=1) s += __shfl_xor(s, off);
    __shared__ float ws4[4];
    if ((threadIdx.x & 63) == 0) ws4[threadIdx.x >> 6] = s;
    __syncthreads();
    if (threadIdx.x == 0) out[0] = (ws4[0]+ws4[1]+ws4[2]+ws4[3]) * (1.f/(float)(M_*CF_));
}

// ---------------------------------------------------------------------------
// Host
// ---------------------------------------------------------------------------
static constexpr size_t X_OFF     = 0;            // f32 x        25,165,824 B
static constexpr size_t H_OFF     = 25165824;     // bf16 h/xb    12,582,912 B
static constexpr size_t O_OFF     = 37748736;     // bf16 o/u/idx 12,582,912 B
static constexpr size_t QKV_OFF   = 50331648;     // bf16 q,k,v   37,748,736 B
static constexpr size_t WQKV_OFF  = 88080384;     // bf16         25,165,824 B
static constexpr size_t WPROJ_OFF = 113246208;    // bf16          8,388,608 B
static constexpr size_t W1_OFF    = 121634816;    // bf16          8,388,608 B
static constexpr size_t W2_OFF    = 130023424;    // bf16          8,388,608 B
static constexpr size_t WEMB_OFF  = 138412032;    // bf16            131,072 B
static constexpr size_t WFIN_OFF  = 138543104;    // bf16            131,072 B
static constexpr size_t PART_OFF  = 138674176;    // f32               4,096 B

extern "C" void kernel_launch(void* const* d_in, const int* in_sizes, int n_in,
                              void* d_out, int out_size, void* d_ws, size_t ws_size,
                              hipStream_t stream)
{
    const float* index   = (const float*)d_in[0];
    const float* targets = (const float*)d_in[1];
    const float* W_embed = (const float*)d_in[2];
    const float* b_embed = (const float*)d_in[3];
    const float* pe      = (const float*)d_in[4];
    const float* lpe     = (const float*)d_in[5];
    const float* Wq      = (const float*)d_in[6];
    const float* Wk      = (const float*)d_in[7];
    const float* Wv      = (const float*)d_in[8];
    const float* Wproj   = (const float*)d_in[9];
    const float* bproj   = (const float*)d_in[10];
    const float* ln1g    = (const float*)d_in[11];
    const float* ln1b    = (const float*)d_in[12];
    const float* ln2g    = (const float*)d_in[13];
    const float* ln2b    = (const float*)d_in[14];
    const float* W1      = (const float*)d_in[15];
    const float* b1      = (const float*)d_in[16];
    const float* W2      = (const float*)d_in[17];
    const float* b2      = (const float*)d_in[18];
    const float* Wfin    = (const float*)d_in[19];
    const float* bfin    = (const float*)d_in[20];

    char* ws = (char*)d_ws;
    float*          x     = (float*)(ws + X_OFF);
    unsigned short* hbuf  = (unsigned short*)(ws + H_OFF);
    unsigned short* obuf  = (unsigned short*)(ws + O_OFF);
    unsigned short* qkv   = (unsigned short*)(ws + QKV_OFF);
    unsigned short* wqkvp = (unsigned short*)(ws + WQKV_OFF);
    unsigned short* wprojp= (unsigned short*)(ws + WPROJ_OFF);
    unsigned short* w1p   = (unsigned short*)(ws + W1_OFF);
    unsigned short* w2p   = (unsigned short*)(ws + W2_OFF);
    unsigned short* wembp = (unsigned short*)(ws + WEMB_OFF);
    unsigned short* wfinp = (unsigned short*)(ws + WFIN_OFF);
    float*          part  = (float*)(ws + PART_OFF);
    float*          logits= (float*)d_out;

    // pack weights to bf16 B^T layouts
    pack_qkv_k<<<49152, 256, 0, stream>>>(Wq, Wk, Wv, wqkvp);
    pack_t_k<<<16384, 256, 0, stream>>>(Wproj, wprojp, 512, 512, 4194304);
    pack_t_k<<<16384, 256, 0, stream>>>(W1,    w1p,    512, 512, 4194304);
    pack_t_k<<<16384, 256, 0, stream>>>(W2,    w2p,    512, 512, 4194304);
    pack_t_k<<<256,   256, 0, stream>>>(W_embed, wembp, 128, 512, 65536);
    pack_t_k<<<256,   256, 0, stream>>>(Wfin,    wfinp, 512, 128, 65536);

    // embed: x = bf16(index) @ Wemb^T + b + pe + lpe
    cast4_k<<<1536, 256, 0, stream>>>(index, obuf, 393216);
    gemm_k<0><<<dim3(96,4), 256, 0, stream>>>(obuf, wembp, b_embed, pe, lpe, x, nullptr, 128);

    for (int l = 0; l < L_; ++l){
        ln_k<<<3072, 256, 0, stream>>>(x, ln1g + l*512, ln1b + l*512, hbuf);
        gemm_k<1><<<dim3(96,12), 256, 0, stream>>>(hbuf, wqkvp + (size_t)l*786432,
                                                   nullptr, nullptr, nullptr, nullptr, qkv, 512);
        attn_k<<<dim3(6,512), 256, 0, stream>>>(qkv, qkv + 6291456, qkv + 2*6291456, obuf);
        gemm_k<2><<<dim3(96,4), 256, 0, stream>>>(obuf, wprojp + (size_t)l*262144,
                                                  bproj + l*512, nullptr, nullptr, x, nullptr, 512);
        ln_k<<<3072, 256, 0, stream>>>(x, ln2g + l*512, ln2b + l*512, hbuf);
        gemm_k<3><<<dim3(96,4), 256, 0, stream>>>(hbuf, w1p + (size_t)l*262144,
                                                  b1 + l*512, nullptr, nullptr, nullptr, obuf, 512);
        gemm_k<2><<<dim3(96,4), 256, 0, stream>>>(obuf, w2p + (size_t)l*262144,
                                                  b2 + l*512, nullptr, nullptr, x, nullptr, 512);
    }

    // final: logits = bf16(x) @ Wfin^T + b_final ; loss = mean((logits-targets)^2)
    cast4_k<<<6144, 256, 0, stream>>>(x, hbuf, 1572864);
    gemm_k<4><<<dim3(96,1), 256, 0, stream>>>(hbuf, wfinp, bfin, nullptr, nullptr, logits, nullptr, 512);
    loss1_k<<<1024, 256, 0, stream>>>(logits, targets, part);
    loss2_k<<<1, 256, 0, stream>>>(part, logits + 1572864);
}

// Round 2
// 3357.557 us; speedup vs baseline: 1.2453x; 1.2453x over previous
//
#include <hip/hip_runtime.h>
#include <hip/hip_bf16.h>

#define B_   32
#define T_   384
#define CF_  128
#define D_   512
#define H_   16
#define HD_  32
#define L_   16
#define HID_ 512
#define M_   (B_*T_)   // 12288

typedef __bf16 bf16x8 __attribute__((ext_vector_type(8)));
typedef float  f32x4  __attribute__((ext_vector_type(4)));

__device__ __forceinline__ float bf2f(unsigned short u){
    unsigned int x = ((unsigned int)u) << 16;
    return __builtin_bit_cast(float, x);
}
__device__ __forceinline__ unsigned short f2bf(float f){
    unsigned int u = __builtin_bit_cast(unsigned int, f);
    u += 0x7FFFu + ((u >> 16) & 1u);
    return (unsigned short)(u >> 16);
}

// ---------------------------------------------------------------------------
// Generic bf16 MFMA GEMM: C[M][N] = A[M][K] * Bt[N][K]^T  (Bt = B transposed)
// 128x128 tile, 256 threads (4 waves as 2x2 of 64x64), BK=32, double-buffered
// LDS with XOR slot swizzle (conflict-free ds_read_b128).
// ---------------------------------------------------------------------------
template<int EPI>
__global__ __launch_bounds__(256) void gemm_k(
    const unsigned short* __restrict__ A,
    const unsigned short* __restrict__ Bt,
    const float* __restrict__ aux0,   // bias
    const float* __restrict__ aux1,   // pe
    const float* __restrict__ aux2,   // learnable pe
    float* __restrict__ fout,
    unsigned short* __restrict__ bout,
    int K)
{
    __shared__ unsigned short lA[2][128*32];
    __shared__ unsigned short lB[2][128*32];

    const int tid  = threadIdx.x;
    const int lane = tid & 63;
    const int w    = tid >> 6;
    const int wm   = w >> 1, wn = w & 1;
    const int li   = lane & 15, ls = lane >> 4;
    const int m0   = blockIdx.x * 128;
    const int n0   = blockIdx.y * 128;
    const int nkt  = K >> 5;

    const int e0 = tid, e1 = tid + 256;
    const int r0 = e0 >> 2, s0 = e0 & 3;
    const int r1 = e1 >> 2, s1 = e1 & 3;
    const int w0 = r0*32 + ((s0 ^ ((r0>>1)&3))*8);
    const int w1 = r1*32 + ((s1 ^ ((r1>>1)&3))*8);
    const unsigned short* Ar0 = A  + (size_t)(m0 + r0)*K + s0*8;
    const unsigned short* Ar1 = A  + (size_t)(m0 + r1)*K + s1*8;
    const unsigned short* Br0 = Bt + (size_t)(n0 + r0)*K + s0*8;
    const unsigned short* Br1 = Bt + (size_t)(n0 + r1)*K + s1*8;

    uint4 ra0 = *(const uint4*)(Ar0);
    uint4 ra1 = *(const uint4*)(Ar1);
    uint4 rb0 = *(const uint4*)(Br0);
    uint4 rb1 = *(const uint4*)(Br1);

    f32x4 acc[4][4];
    #pragma unroll
    for (int i=0;i<4;i++)
        #pragma unroll
        for (int j=0;j<4;j++) acc[i][j] = (f32x4){0.f,0.f,0.f,0.f};

    int cur = 0;
    for (int kt = 0; kt < nkt; ++kt){
        *(uint4*)&lA[cur][w0] = ra0;
        *(uint4*)&lA[cur][w1] = ra1;
        *(uint4*)&lB[cur][w0] = rb0;
        *(uint4*)&lB[cur][w1] = rb1;
        __syncthreads();
        if (kt + 1 < nkt){
            const int ko = (kt+1)*32;
            ra0 = *(const uint4*)(Ar0 + ko);
            ra1 = *(const uint4*)(Ar1 + ko);
            rb0 = *(const uint4*)(Br0 + ko);
            rb1 = *(const uint4*)(Br1 + ko);
        }
        bf16x8 af[4], bf[4];
        #pragma unroll
        for (int f=0; f<4; ++f){
            const int rA = wm*64 + f*16 + li;
            af[f] = *(const bf16x8*)&lA[cur][rA*32 + ((ls ^ ((rA>>1)&3))*8)];
            const int rB = wn*64 + f*16 + li;
            bf[f] = *(const bf16x8*)&lB[cur][rB*32 + ((ls ^ ((rB>>1)&3))*8)];
        }
        #pragma unroll
        for (int i=0;i<4;i++)
            #pragma unroll
            for (int j=0;j<4;j++)
                acc[i][j] = __builtin_amdgcn_mfma_f32_16x16x32_bf16(af[i], bf[j], acc[i][j], 0, 0, 0);
        cur ^= 1;
    }

    // epilogue: D layout col = lane&15, row = (lane>>4)*4 + t  (verified m89)
    #pragma unroll
    for (int i=0;i<4;i++){
        #pragma unroll
        for (int j=0;j<4;j++){
            #pragma unroll
            for (int t=0;t<4;t++){
                const int row = m0 + wm*64 + i*16 + ls*4 + t;
                const int col = n0 + wn*64 + j*16 + li;
                const float v = acc[i][j][t];
                if constexpr (EPI == 0){
                    const int tt = row % T_;
                    fout[row*D_ + col] = v + aux0[col] + aux1[tt*D_ + col] + aux2[tt*D_ + col];
                } else if constexpr (EPI == 1){
                    const int mat = col >> 9, nl = col & 511;
                    const int hh = nl >> 5, dd = nl & 31;
                    const int bb = row / T_, tt = row % T_;
                    bout[mat*(M_*D_) + (((bb*H_ + hh)*T_ + tt)*HD_) + dd] = f2bf(v);
                } else if constexpr (EPI == 2){
                    fout[row*D_ + col] += v + aux0[col];
                } else if constexpr (EPI == 3){
                    const float r = v + aux0[col];
                    bout[row*HID_ + col] = f2bf(r > 0.f ? r : 0.f);
                } else {
                    fout[row*CF_ + col] = v + aux0[col];
                }
            }
        }
    }
}

// ---------------------------------------------------------------------------
// LayerNorm: one wave per row of 512, out bf16
// ---------------------------------------------------------------------------
__global__ __launch_bounds__(256) void ln_k(const float* __restrict__ x,
                                            const float* __restrict__ g,
                                            const float* __restrict__ b,
                                            unsigned short* __restrict__ out)
{
    const int w = threadIdx.x >> 6, lane = threadIdx.x & 63;
    const int row = blockIdx.x*4 + w;
    const float* xr = x + (size_t)row*D_;
    const float4 a = *(const float4*)(xr + lane*8);
    const float4 c = *(const float4*)(xr + lane*8 + 4);
    float s  = a.x+a.y+a.z+a.w + c.x+c.y+c.z+c.w;
    float q2 = a.x*a.x+a.y*a.y+a.z*a.z+a.w*a.w + c.x*c.x+c.y*c.y+c.z*c.z+c.w*c.w;
    #pragma unroll
    for (int off=32; off; off>>=1){
        s  += __shfl_xor(s,  off);
        q2 += __shfl_xor(q2, off);
    }
    const float mean = s * (1.f/512.f);
    const float var  = q2 * (1.f/512.f) - mean*mean;
    const float rstd = rsqrtf(var + 1e-6f);
    const float4 gA = *(const float4*)(g + lane*8);
    const float4 gB = *(const float4*)(g + lane*8 + 4);
    const float4 bA = *(const float4*)(b + lane*8);
    const float4 bB = *(const float4*)(b + lane*8 + 4);
    alignas(16) unsigned short o8[8];
    o8[0] = f2bf((a.x-mean)*rstd*gA.x + bA.x);
    o8[1] = f2bf((a.y-mean)*rstd*gA.y + bA.y);
    o8[2] = f2bf((a.z-mean)*rstd*gA.z + bA.z);
    o8[3] = f2bf((a.w-mean)*rstd*gA.w + bA.w);
    o8[4] = f2bf((c.x-mean)*rstd*gB.x + bB.x);
    o8[5] = f2bf((c.y-mean)*rstd*gB.y + bB.y);
    o8[6] = f2bf((c.z-mean)*rstd*gB.z + bB.z);
    o8[7] = f2bf((c.w-mean)*rstd*gB.w + bB.w);
    *(uint4*)(out + (size_t)row*D_ + lane*8) = *(const uint4*)o8;
}

// ---------------------------------------------------------------------------
// Causal attention, scale = 1/sqrt(512). q,k,v: [BH][T][32] bf16.
// 1-D grid (3072), XCD-chunk swizzled so the 6 t-tiles of one bh share an
// XCD L2. Coalesced V load + in-LDS dword-pair transpose; K prefetch 1-deep.
// ---------------------------------------------------------------------------
__global__ __launch_bounds__(256) void attn_k(const unsigned short* __restrict__ q,
                                              const unsigned short* __restrict__ k,
                                              const unsigned short* __restrict__ v,
                                              unsigned short* __restrict__ o)
{
    __shared__ unsigned short S[64][392];
    __shared__ unsigned short Vt[32][392];
    __shared__ float rowsum[64];

    // bijective XCD-chunk swizzle: 3072 = 8 XCDs * 384
    const int orig = blockIdx.x;
    const int wg   = (orig & 7)*384 + (orig >> 3);
    const int bh   = wg / 6;
    const int t0   = (wg - bh*6) * 64;

    const int tid = threadIdx.x;
    const int lane = tid & 63, w = tid >> 6;
    const int li = lane & 15, ls = lane >> 4;
    const unsigned short* qb = q + (size_t)bh*(T_*HD_);
    const unsigned short* kb = k + (size_t)bh*(T_*HD_);
    const unsigned short* vb = v + (size_t)bh*(T_*HD_);

    // --- stage V transposed (only the causally needed s < t0+64) ---
    // read pairs of v rows coalesced (uint4), write Vt[d][s..s+1] as dwords
    const int nS = t0 + 64;
    const int items = (nS >> 1) * 4;           // (s-pairs) x (4 chunks of 8 d)
    for (int it = tid; it < items; it += 256){
        const int p  = it >> 2;
        const int d0 = (it & 3) << 3;
        const int s  = p << 1;
        const uint4 va0 = *(const uint4*)(vb + s*HD_ + d0);
        const uint4 va1 = *(const uint4*)(vb + (s+1)*HD_ + d0);
        const unsigned short* a16 = (const unsigned short*)&va0;
        const unsigned short* b16 = (const unsigned short*)&va1;
        #pragma unroll
        for (int j=0;j<8;j++){
            const unsigned int dw = (unsigned int)a16[j] | ((unsigned int)b16[j] << 16);
            *(unsigned int*)&Vt[d0+j][s] = dw;
        }
    }

    const int trow0 = t0 + w*16;
    const bf16x8 qa = *(const bf16x8*)(qb + (trow0 + li)*HD_ + ls*8);
    const int nst16 = (trow0 >> 4) + 1;
    const float scale = 0.04419417382415922f;   // 1/sqrt(512)

    // --- QK^T with 1-deep K prefetch ---
    bf16x8 kf = *(const bf16x8*)(kb + li*HD_ + ls*8);
    for (int st = 0; st < nst16; ++st){
        bf16x8 kn;
        if (st + 1 < nst16)
            kn = *(const bf16x8*)(kb + ((st+1)*16 + li)*HD_ + ls*8);
        f32x4 sa = (f32x4){0.f,0.f,0.f,0.f};
        sa = __builtin_amdgcn_mfma_f32_16x16x32_bf16(qa, kf, sa, 0, 0, 0);
        #pragma unroll
        for (int j=0;j<4;j++){
            const int tr = w*16 + ls*4 + j;
            S[tr][st*16 + li] = f2bf(sa[j] * scale);
        }
        kf = kn;
    }
    __syncthreads();

    // --- wave-parallel softmax: 4 lanes per row, unnormalized P in place ---
    {
        const int r  = w*16 + li;
        const int tg = t0 + r;
        const int ns = tg + 1;
        const int send = ((trow0 + 16 + 31) >> 5) << 5;
        float m = -1e30f;
        for (int s = ls; s < ns; s += 4) m = fmaxf(m, bf2f(S[r][s]));
        m = fmaxf(m, __shfl_xor(m, 16));
        m = fmaxf(m, __shfl_xor(m, 32));
        float sum = 0.f;
        for (int s = ls; s < ns; s += 4){
            const float e = __expf(bf2f(S[r][s]) - m);
            sum += e;
            S[r][s] = f2bf(e);
        }
        for (int s = (ns & ~3) + ls; s < send; s += 4)
            if (s >= ns) S[r][s] = 0;
        sum += __shfl_xor(sum, 16);
        sum += __shfl_xor(sum, 32);
        if (ls == 0) rowsum[r] = sum;
    }
    __syncthreads();

    // --- PV ---
    const int nst = (trow0 + 16 + 31) >> 5;
    f32x4 oa[2] = { (f32x4){0.f,0.f,0.f,0.f}, (f32x4){0.f,0.f,0.f,0.f} };
    for (int ss = 0; ss < nst; ++ss){
        const bf16x8 pf = *(const bf16x8*)&S[w*16 + li][ss*32 + ls*8];
        #pragma unroll
        for (int df=0; df<2; ++df){
            const bf16x8 vf = *(const bf16x8*)&Vt[df*16 + li][ss*32 + ls*8];
            oa[df] = __builtin_amdgcn_mfma_f32_16x16x32_bf16(pf, vf, oa[df], 0, 0, 0);
        }
    }
    const int bb = bh >> 4, hh = bh & 15;
    #pragma unroll
    for (int df=0; df<2; ++df){
        #pragma unroll
        for (int j=0;j<4;j++){
            const int tr = w*16 + ls*4 + j;
            const int tg = t0 + tr;
            const float val = oa[df][j] / rowsum[tr];
            o[(size_t)(bb*T_ + tg)*D_ + hh*HD_ + df*16 + li] = f2bf(val);
        }
    }
}

// ---------------------------------------------------------------------------
// Weight packing / casts / loss
// ---------------------------------------------------------------------------
__global__ void pack_qkv_k(const float* __restrict__ Wq, const float* __restrict__ Wk,
                           const float* __restrict__ Wv, unsigned short* __restrict__ dst)
{
    const int i = blockIdx.x*256 + threadIdx.x;        // 12,582,912 total
    const int l  = i / 786432;  const int r  = i - l*786432;
    const int mat= r / 262144;  const int r2 = r - mat*262144;
    const int n  = r2 >> 9;     const int kk = r2 & 511;
    const int hh = n >> 5, dd = n & 31;
    const float* src = (mat==0) ? Wq : (mat==1) ? Wk : Wv;
    dst[i] = f2bf(src[((size_t)(l*H_ + hh)*D_ + kk)*HD_ + dd]);
}

__global__ void pack_t_k(const float* __restrict__ src, unsigned short* __restrict__ dst,
                         int K, int N, int total)
{
    const int i = blockIdx.x*256 + threadIdx.x;
    if (i >= total) return;
    const int mn = K*N;
    const int l = i / mn;  const int r = i - l*mn;
    const int n = r / K;   const int kk = r - n*K;
    dst[i] = f2bf(src[(size_t)l*mn + (size_t)kk*N + n]);
}

__global__ void cast4_k(const float* __restrict__ src, unsigned short* __restrict__ dst, int total4)
{
    const int i = blockIdx.x*256 + threadIdx.x;
    if (i >= total4) return;
    const float4 vv = ((const float4*)src)[i];
    alignas(8) unsigned short t[4] = { f2bf(vv.x), f2bf(vv.y), f2bf(vv.z), f2bf(vv.w) };
    *(uint2*)(dst + (size_t)i*4) = *(const uint2*)t;
}

__global__ __launch_bounds__(256) void loss1_k(const float* __restrict__ logits,
                                               const float* __restrict__ tgt,
                                               float* __restrict__ part)
{
    float s = 0.f;
    for (int i = blockIdx.x*256 + threadIdx.x; i < M_*CF_; i += 256*1024){
        const float d = logits[i] - tgt[i];
        s += d*d;
    }
    #pragma unroll
    for (int off=32; off; off>>=1) s += __shfl_xor(s, off);
    __shared__ float ws4[4];
    if ((threadIdx.x & 63) == 0) ws4[threadIdx.x >> 6] = s;
    __syncthreads();
    if (threadIdx.x == 0) part[blockIdx.x] = ws4[0]+ws4[1]+ws4[2]+ws4[3];
}

__global__ __launch_bounds__(256) void loss2_k(const float* __restrict__ part,
                                               float* __restrict__ out)
{
    float s = 0.f;
    for (int i = threadIdx.x; i < 1024; i += 256) s += part[i];
    #pragma unroll
    for (int off=32; off; off>>=1) s += __shfl_xor(s, off);
    __shared__ float ws4[4];
    if ((threadIdx.x & 63) == 0) ws4[threadIdx.x >> 6] = s;
    __syncthreads();
    if (threadIdx.x == 0) out[0] = (ws4[0]+ws4[1]+ws4[2]+ws4[3]) * (1.f/(float)(M_*CF_));
}

// ---------------------------------------------------------------------------
// Host
// ---------------------------------------------------------------------------
static constexpr size_t X_OFF     = 0;            // f32 x        25,165,824 B
static constexpr size_t H_OFF     = 25165824;     // bf16 h/xb    12,582,912 B
static constexpr size_t O_OFF     = 37748736;     // bf16 o/u/idx 12,582,912 B
static constexpr size_t QKV_OFF   = 50331648;     // bf16 q,k,v   37,748,736 B
static constexpr size_t WQKV_OFF  = 88080384;     // bf16         25,165,824 B
static constexpr size_t WPROJ_OFF = 113246208;    // bf16          8,388,608 B
static constexpr size_t W1_OFF    = 121634816;    // bf16          8,388,608 B
static constexpr size_t W2_OFF    = 130023424;    // bf16          8,388,608 B
static constexpr size_t WEMB_OFF  = 138412032;    // bf16            131,072 B
static constexpr size_t WFIN_OFF  = 138543104;    // bf16            131,072 B
static constexpr size_t PART_OFF  = 138674176;    // f32               4,096 B

extern "C" void kernel_launch(void* const* d_in, const int* in_sizes, int n_in,
                              void* d_out, int out_size, void* d_ws, size_t ws_size,
                              hipStream_t stream)
{
    const float* index   = (const float*)d_in[0];
    const float* targets = (const float*)d_in[1];
    const float* W_embed = (const float*)d_in[2];
    const float* b_embed = (const float*)d_in[3];
    const float* pe      = (const float*)d_in[4];
    const float* lpe     = (const float*)d_in[5];
    const float* Wq      = (const float*)d_in[6];
    const float* Wk      = (const float*)d_in[7];
    const float* Wv      = (const float*)d_in[8];
    const float* Wproj   = (const float*)d_in[9];
    const float* bproj   = (const float*)d_in[10];
    const float* ln1g    = (const float*)d_in[11];
    const float* ln1b    = (const float*)d_in[12];
    const float* ln2g    = (const float*)d_in[13];
    const float* ln2b    = (const float*)d_in[14];
    const float* W1      = (const float*)d_in[15];
    const float* b1      = (const float*)d_in[16];
    const float* W2      = (const float*)d_in[17];
    const float* b2      = (const float*)d_in[18];
    const float* Wfin    = (const float*)d_in[19];
    const float* bfin    = (const float*)d_in[20];

    char* ws = (char*)d_ws;
    float*          x     = (float*)(ws + X_OFF);
    unsigned short* hbuf  = (unsigned short*)(ws + H_OFF);
    unsigned short* obuf  = (unsigned short*)(ws + O_OFF);
    unsigned short* qkv   = (unsigned short*)(ws + QKV_OFF);
    unsigned short* wqkvp = (unsigned short*)(ws + WQKV_OFF);
    unsigned short* wprojp= (unsigned short*)(ws + WPROJ_OFF);
    unsigned short* w1p   = (unsigned short*)(ws + W1_OFF);
    unsigned short* w2p   = (unsigned short*)(ws + W2_OFF);
    unsigned short* wembp = (unsigned short*)(ws + WEMB_OFF);
    unsigned short* wfinp = (unsigned short*)(ws + WFIN_OFF);
    float*          part  = (float*)(ws + PART_OFF);
    float*          logits= (float*)d_out;

    // pack weights to bf16 B^T layouts
    pack_qkv_k<<<49152, 256, 0, stream>>>(Wq, Wk, Wv, wqkvp);
    pack_t_k<<<16384, 256, 0, stream>>>(Wproj, wprojp, 512, 512, 4194304);
    pack_t_k<<<16384, 256, 0, stream>>>(W1,    w1p,    512, 512, 4194304);
    pack_t_k<<<16384, 256, 0, stream>>>(W2,    w2p,    512, 512, 4194304);
    pack_t_k<<<256,   256, 0, stream>>>(W_embed, wembp, 128, 512, 65536);
    pack_t_k<<<256,   256, 0, stream>>>(Wfin,    wfinp, 512, 128, 65536);

    // embed: x = bf16(index) @ Wemb^T + b + pe + lpe
    cast4_k<<<1536, 256, 0, stream>>>(index, obuf, 393216);
    gemm_k<0><<<dim3(96,4), 256, 0, stream>>>(obuf, wembp, b_embed, pe, lpe, x, nullptr, 128);

    for (int l = 0; l < L_; ++l){
        ln_k<<<3072, 256, 0, stream>>>(x, ln1g + l*512, ln1b + l*512, hbuf);
        gemm_k<1><<<dim3(96,12), 256, 0, stream>>>(hbuf, wqkvp + (size_t)l*786432,
                                                   nullptr, nullptr, nullptr, nullptr, qkv, 512);
        attn_k<<<3072, 256, 0, stream>>>(qkv, qkv + 6291456, qkv + 2*6291456, obuf);
        gemm_k<2><<<dim3(96,4), 256, 0, stream>>>(obuf, wprojp + (size_t)l*262144,
                                                  bproj + l*512, nullptr, nullptr, x, nullptr, 512);
        ln_k<<<3072, 256, 0, stream>>>(x, ln2g + l*512, ln2b + l*512, hbuf);
        gemm_k<3><<<dim3(96,4), 256, 0, stream>>>(hbuf, w1p + (size_t)l*262144,
                                                  b1 + l*512, nullptr, nullptr, nullptr, obuf, 512);
        gemm_k<2><<<dim3(96,4), 256, 0, stream>>>(obuf, w2p + (size_t)l*262144,
                                                  b2 + l*512, nullptr, nullptr, x, nullptr, 512);
    }

    // final: logits = bf16(x) @ Wfin^T + b_final ; loss = mean((logits-targets)^2)
    cast4_k<<<6144, 256, 0, stream>>>(x, hbuf, 1572864);
    gemm_k<4><<<dim3(96,1), 256, 0, stream>>>(hbuf, wfinp, bfin, nullptr, nullptr, logits, nullptr, 512);
    loss1_k<<<1024, 256, 0, stream>>>(logits, targets, part);
    loss2_k<<<1, 256, 0, stream>>>(part, logits + 1572864);
}

// Round 3
// 2395.636 us; speedup vs baseline: 1.7453x; 1.4015x over previous
//
#include <hip/hip_runtime.h>
#include <hip/hip_bf16.h>

#define B_   32
#define T_   384
#define CF_  128
#define D_   512
#define H_   16
#define HD_  32
#define L_   16
#define HID_ 512
#define M_   (B_*T_)   // 12288

typedef __bf16 bf16x8 __attribute__((ext_vector_type(8)));
typedef float  f32x4  __attribute__((ext_vector_type(4)));

__device__ __forceinline__ float bf2f(unsigned short u){
    unsigned int x = ((unsigned int)u) << 16;
    return __builtin_bit_cast(float, x);
}
__device__ __forceinline__ unsigned short f2bf(float f){
    unsigned int u = __builtin_bit_cast(unsigned int, f);
    u += 0x7FFFu + ((u >> 16) & 1u);
    return (unsigned short)(u >> 16);
}

// ---------------------------------------------------------------------------
// Generic bf16 MFMA GEMM: C[M][N] = A[M][K] * Bt[N][K]^T  (Bt = B transposed)
// 128x128 tile, 256 threads (4 waves as 2x2 of 64x64), BK=32, double-buffered
// LDS with XOR slot swizzle (conflict-free ds_read_b128).
// ---------------------------------------------------------------------------
template<int EPI>
__global__ __launch_bounds__(256) void gemm_k(
    const unsigned short* __restrict__ A,
    const unsigned short* __restrict__ Bt,
    const float* __restrict__ aux0,   // bias
    const float* __restrict__ aux1,   // pe
    const float* __restrict__ aux2,   // learnable pe
    float* __restrict__ fout,
    unsigned short* __restrict__ bout,
    int K)
{
    __shared__ unsigned short lA[2][128*32];
    __shared__ unsigned short lB[2][128*32];

    const int tid  = threadIdx.x;
    const int lane = tid & 63;
    const int w    = tid >> 6;
    const int wm   = w >> 1, wn = w & 1;
    const int li   = lane & 15, ls = lane >> 4;
    const int m0   = blockIdx.x * 128;
    const int n0   = blockIdx.y * 128;
    const int nkt  = K >> 5;

    const int e0 = tid, e1 = tid + 256;
    const int r0 = e0 >> 2, s0 = e0 & 3;
    const int r1 = e1 >> 2, s1 = e1 & 3;
    const int w0 = r0*32 + ((s0 ^ ((r0>>1)&3))*8);
    const int w1 = r1*32 + ((s1 ^ ((r1>>1)&3))*8);
    const unsigned short* Ar0 = A  + (size_t)(m0 + r0)*K + s0*8;
    const unsigned short* Ar1 = A  + (size_t)(m0 + r1)*K + s1*8;
    const unsigned short* Br0 = Bt + (size_t)(n0 + r0)*K + s0*8;
    const unsigned short* Br1 = Bt + (size_t)(n0 + r1)*K + s1*8;

    uint4 ra0 = *(const uint4*)(Ar0);
    uint4 ra1 = *(const uint4*)(Ar1);
    uint4 rb0 = *(const uint4*)(Br0);
    uint4 rb1 = *(const uint4*)(Br1);

    f32x4 acc[4][4];
    #pragma unroll
    for (int i=0;i<4;i++)
        #pragma unroll
        for (int j=0;j<4;j++) acc[i][j] = (f32x4){0.f,0.f,0.f,0.f};

    int cur = 0;
    for (int kt = 0; kt < nkt; ++kt){
        *(uint4*)&lA[cur][w0] = ra0;
        *(uint4*)&lA[cur][w1] = ra1;
        *(uint4*)&lB[cur][w0] = rb0;
        *(uint4*)&lB[cur][w1] = rb1;
        __syncthreads();
        if (kt + 1 < nkt){
            const int ko = (kt+1)*32;
            ra0 = *(const uint4*)(Ar0 + ko);
            ra1 = *(const uint4*)(Ar1 + ko);
            rb0 = *(const uint4*)(Br0 + ko);
            rb1 = *(const uint4*)(Br1 + ko);
        }
        bf16x8 af[4], bf[4];
        #pragma unroll
        for (int f=0; f<4; ++f){
            const int rA = wm*64 + f*16 + li;
            af[f] = *(const bf16x8*)&lA[cur][rA*32 + ((ls ^ ((rA>>1)&3))*8)];
            const int rB = wn*64 + f*16 + li;
            bf[f] = *(const bf16x8*)&lB[cur][rB*32 + ((ls ^ ((rB>>1)&3))*8)];
        }
        #pragma unroll
        for (int i=0;i<4;i++)
            #pragma unroll
            for (int j=0;j<4;j++)
                acc[i][j] = __builtin_amdgcn_mfma_f32_16x16x32_bf16(af[i], bf[j], acc[i][j], 0, 0, 0);
        cur ^= 1;
    }

    // epilogue: D layout col = lane&15, row = (lane>>4)*4 + t  (verified m89)
    #pragma unroll
    for (int i=0;i<4;i++){
        #pragma unroll
        for (int j=0;j<4;j++){
            #pragma unroll
            for (int t=0;t<4;t++){
                const int row = m0 + wm*64 + i*16 + ls*4 + t;
                const int col = n0 + wn*64 + j*16 + li;
                const float v = acc[i][j][t];
                if constexpr (EPI == 0){
                    const int tt = row % T_;
                    fout[row*D_ + col] = v + aux0[col] + aux1[tt*D_ + col] + aux2[tt*D_ + col];
                } else if constexpr (EPI == 1){
                    const int mat = col >> 9, nl = col & 511;
                    const int hh = nl >> 5, dd = nl & 31;
                    const int bb = row / T_, tt = row % T_;
                    bout[mat*(M_*D_) + (((bb*H_ + hh)*T_ + tt)*HD_) + dd] = f2bf(v);
                } else if constexpr (EPI == 2){
                    fout[row*D_ + col] += v + aux0[col];
                } else if constexpr (EPI == 3){
                    const float r = v + aux0[col];
                    bout[row*HID_ + col] = f2bf(r > 0.f ? r : 0.f);
                } else {
                    fout[row*CF_ + col] = v + aux0[col];
                }
            }
        }
    }
}

// ---------------------------------------------------------------------------
// LayerNorm: one wave per row of 512, out bf16
// ---------------------------------------------------------------------------
__global__ __launch_bounds__(256) void ln_k(const float* __restrict__ x,
                                            const float* __restrict__ g,
                                            const float* __restrict__ b,
                                            unsigned short* __restrict__ out)
{
    const int w = threadIdx.x >> 6, lane = threadIdx.x & 63;
    const int row = blockIdx.x*4 + w;
    const float* xr = x + (size_t)row*D_;
    const float4 a = *(const float4*)(xr + lane*8);
    const float4 c = *(const float4*)(xr + lane*8 + 4);
    float s  = a.x+a.y+a.z+a.w + c.x+c.y+c.z+c.w;
    float q2 = a.x*a.x+a.y*a.y+a.z*a.z+a.w*a.w + c.x*c.x+c.y*c.y+c.z*c.z+c.w*c.w;
    #pragma unroll
    for (int off=32; off; off>>=1){
        s  += __shfl_xor(s,  off);
        q2 += __shfl_xor(q2, off);
    }
    const float mean = s * (1.f/512.f);
    const float var  = q2 * (1.f/512.f) - mean*mean;
    const float rstd = rsqrtf(var + 1e-6f);
    const float4 gA = *(const float4*)(g + lane*8);
    const float4 gB = *(const float4*)(g + lane*8 + 4);
    const float4 bA = *(const float4*)(b + lane*8);
    const float4 bB = *(const float4*)(b + lane*8 + 4);
    alignas(16) unsigned short o8[8];
    o8[0] = f2bf((a.x-mean)*rstd*gA.x + bA.x);
    o8[1] = f2bf((a.y-mean)*rstd*gA.y + bA.y);
    o8[2] = f2bf((a.z-mean)*rstd*gA.z + bA.z);
    o8[3] = f2bf((a.w-mean)*rstd*gA.w + bA.w);
    o8[4] = f2bf((c.x-mean)*rstd*gB.x + bB.x);
    o8[5] = f2bf((c.y-mean)*rstd*gB.y + bB.y);
    o8[6] = f2bf((c.z-mean)*rstd*gB.z + bB.z);
    o8[7] = f2bf((c.w-mean)*rstd*gB.w + bB.w);
    *(uint4*)(out + (size_t)row*D_ + lane*8) = *(const uint4*)o8;
}

// ---------------------------------------------------------------------------
// Causal flash attention, scale = 1/sqrt(512). q,k,v: [BH][T][32] bf16.
// 1-D grid (3072), XCD-chunk swizzled. No S matrix: online softmax in
// registers, P transposed through a tiny per-wave LDS scratch.
// ---------------------------------------------------------------------------
__global__ __launch_bounds__(256) void attn_k(const unsigned short* __restrict__ q,
                                              const unsigned short* __restrict__ k,
                                              const unsigned short* __restrict__ v,
                                              unsigned short* __restrict__ o)
{
    constexpr int VSTR = 408;                    // dword stride 204 = 12 mod 32
    __shared__ unsigned short Vt[32][VSTR];      // 26,112 B
    __shared__ unsigned short Pb[4][16*40];      //  5,120 B (per-wave 16x32, stride 40)

    // bijective XCD-chunk swizzle: 3072 = 8 XCDs * 384
    const int orig = blockIdx.x;
    const int wg   = (orig & 7)*384 + (orig >> 3);
    const int bh   = wg / 6;
    const int t0   = (wg - bh*6) * 64;

    const int tid = threadIdx.x;
    const int lane = tid & 63, w = tid >> 6;
    const int li = lane & 15, ls = lane >> 4;
    const unsigned short* qb = q + (size_t)bh*(T_*HD_);
    const unsigned short* kb = k + (size_t)bh*(T_*HD_);
    const unsigned short* vb = v + (size_t)bh*(T_*HD_);

    // --- stage V transposed (causal range only), coalesced reads ---
    const int nS = t0 + 64;
    const int items = (nS >> 1) * 4;            // (s-pairs) x (4 chunks of 8 d)
    for (int it = tid; it < items; it += 256){
        const int p  = it >> 2;
        const int d0 = (it & 3) << 3;
        const int s  = p << 1;
        const uint4 va0 = *(const uint4*)(vb + s*HD_ + d0);
        const uint4 va1 = *(const uint4*)(vb + (s+1)*HD_ + d0);
        const unsigned short* a16 = (const unsigned short*)&va0;
        const unsigned short* b16 = (const unsigned short*)&va1;
        #pragma unroll
        for (int j=0;j<8;j++)
            *(unsigned int*)&Vt[d0+j][s] = (unsigned int)a16[j] | ((unsigned int)b16[j] << 16);
    }

    const int trow0 = t0 + w*16;                // wave's first q row
    const int rowg  = trow0 + ls*4;             // lane's first accumulated row
    const bf16x8 qa = *(const bf16x8*)(qb + (trow0 + li)*HD_ + ls*8);
    const float scale = 0.04419417382415922f;   // 1/sqrt(512)
    const int nc = (trow0 + 16 + 31) >> 5;      // 32-wide k-chunks

    f32x4 m4 = {-1e30f,-1e30f,-1e30f,-1e30f};
    f32x4 l4 = {0.f,0.f,0.f,0.f};
    f32x4 oa0 = {0.f,0.f,0.f,0.f}, oa1 = {0.f,0.f,0.f,0.f};
    unsigned short* pw = Pb[w];

    __syncthreads();                            // Vt ready

    bf16x8 kf0 = *(const bf16x8*)(kb + (li)*HD_ + ls*8);
    bf16x8 kf1 = *(const bf16x8*)(kb + (16 + li)*HD_ + ls*8);

    for (int c = 0; c < nc; ++c){
        // QK^T (scores in regs: row = ls*4+j, col = c*32 + li (+16))
        f32x4 s0 = {0.f,0.f,0.f,0.f}, s1 = {0.f,0.f,0.f,0.f};
        s0 = __builtin_amdgcn_mfma_f32_16x16x32_bf16(qa, kf0, s0, 0, 0, 0);
        s1 = __builtin_amdgcn_mfma_f32_16x16x32_bf16(qa, kf1, s1, 0, 0, 0);
        if (c + 1 < nc){
            kf0 = *(const bf16x8*)(kb + ((c+1)*32 + li)*HD_ + ls*8);
            kf1 = *(const bf16x8*)(kb + ((c+1)*32 + 16 + li)*HD_ + ls*8);
        }

        const int colg0 = c*32 + li;
        const int colg1 = colg0 + 16;
        float p0[4], p1[4];
        #pragma unroll
        for (int j=0;j<4;j++){
            const int rg = rowg + j;
            float v0 = (colg0 <= rg) ? s0[j]*scale : -1e30f;
            float v1 = (colg1 <= rg) ? s1[j]*scale : -1e30f;
            // chunk row-max across the 16 li lanes
            float cm = fmaxf(v0, v1);
            cm = fmaxf(cm, __shfl_xor(cm, 1));
            cm = fmaxf(cm, __shfl_xor(cm, 2));
            cm = fmaxf(cm, __shfl_xor(cm, 4));
            cm = fmaxf(cm, __shfl_xor(cm, 8));
            const float mo = m4[j];
            const float mn = fmaxf(mo, cm);
            const float f  = __expf(mo - mn);   // 0 when mo = -1e30
            m4[j] = mn;
            const float e0 = __expf(v0 - mn);
            const float e1 = __expf(v1 - mn);
            l4[j]  = l4[j]*f + e0 + e1;         // per-lane partial row sum
            oa0[j] *= f;  oa1[j] *= f;
            p0[j] = e0;   p1[j] = e1;
        }

        // transpose P (16x32) through per-wave LDS scratch
        #pragma unroll
        for (int j=0;j<4;j++){
            pw[(ls*4+j)*40 + li]      = f2bf(p0[j]);
            pw[(ls*4+j)*40 + 16 + li] = f2bf(p1[j]);
        }
        asm volatile("s_waitcnt lgkmcnt(0)" ::: "memory");
        const bf16x8 pa  = *(const bf16x8*)&pw[li*40 + ls*8];
        const bf16x8 vf0 = *(const bf16x8*)&Vt[li][c*32 + ls*8];
        const bf16x8 vf1 = *(const bf16x8*)&Vt[16 + li][c*32 + ls*8];
        oa0 = __builtin_amdgcn_mfma_f32_16x16x32_bf16(pa, vf0, oa0, 0, 0, 0);
        oa1 = __builtin_amdgcn_mfma_f32_16x16x32_bf16(pa, vf1, oa1, 0, 0, 0);
    }

    // finalize row sums (reduce per-lane partials across li)
    #pragma unroll
    for (int j=0;j<4;j++){
        float s = l4[j];
        s += __shfl_xor(s, 1);
        s += __shfl_xor(s, 2);
        s += __shfl_xor(s, 4);
        s += __shfl_xor(s, 8);
        l4[j] = s;
    }

    const int bb = bh >> 4, hh = bh & 15;
    #pragma unroll
    for (int j=0;j<4;j++){
        const int tg = trow0 + ls*4 + j;
        const float inv = 1.f / l4[j];
        o[(size_t)(bb*T_ + tg)*D_ + hh*HD_ + li]      = f2bf(oa0[j]*inv);
        o[(size_t)(bb*T_ + tg)*D_ + hh*HD_ + 16 + li] = f2bf(oa1[j]*inv);
    }
}

// ---------------------------------------------------------------------------
// Weight packing / casts / loss
// ---------------------------------------------------------------------------
__global__ void pack_qkv_k(const float* __restrict__ Wq, const float* __restrict__ Wk,
                           const float* __restrict__ Wv, unsigned short* __restrict__ dst)
{
    const int i = blockIdx.x*256 + threadIdx.x;        // 12,582,912 total
    const int l  = i / 786432;  const int r  = i - l*786432;
    const int mat= r / 262144;  const int r2 = r - mat*262144;
    const int n  = r2 >> 9;     const int kk = r2 & 511;
    const int hh = n >> 5, dd = n & 31;
    const float* src = (mat==0) ? Wq : (mat==1) ? Wk : Wv;
    dst[i] = f2bf(src[((size_t)(l*H_ + hh)*D_ + kk)*HD_ + dd]);
}

__global__ void pack_t_k(const float* __restrict__ src, unsigned short* __restrict__ dst,
                         int K, int N, int total)
{
    const int i = blockIdx.x*256 + threadIdx.x;
    if (i >= total) return;
    const int mn = K*N;
    const int l = i / mn;  const int r = i - l*mn;
    const int n = r / K;   const int kk = r - n*K;
    dst[i] = f2bf(src[(size_t)l*mn + (size_t)kk*N + n]);
}

__global__ void cast4_k(const float* __restrict__ src, unsigned short* __restrict__ dst, int total4)
{
    const int i = blockIdx.x*256 + threadIdx.x;
    if (i >= total4) return;
    const float4 vv = ((const float4*)src)[i];
    alignas(8) unsigned short t[4] = { f2bf(vv.x), f2bf(vv.y), f2bf(vv.z), f2bf(vv.w) };
    *(uint2*)(dst + (size_t)i*4) = *(const uint2*)t;
}

__global__ __launch_bounds__(256) void loss1_k(const float* __restrict__ logits,
                                               const float* __restrict__ tgt,
                                               float* __restrict__ part)
{
    float s = 0.f;
    for (int i = blockIdx.x*256 + threadIdx.x; i < M_*CF_; i += 256*1024){
        const float d = logits[i] - tgt[i];
        s += d*d;
    }
    #pragma unroll
    for (int off=32; off; off>>=1) s += __shfl_xor(s, off);
    __shared__ float ws4[4];
    if ((threadIdx.x & 63) == 0) ws4[threadIdx.x >> 6] = s;
    __syncthreads();
    if (threadIdx.x == 0) part[blockIdx.x] = ws4[0]+ws4[1]+ws4[2]+ws4[3];
}

__global__ __launch_bounds__(256) void loss2_k(const float* __restrict__ part,
                                               float* __restrict__ out)
{
    float s = 0.f;
    for (int i = threadIdx.x; i < 1024; i += 256) s += part[i];
    #pragma unroll
    for (int off=32; off; off>>=1) s += __shfl_xor(s, off);
    __shared__ float ws4[4];
    if ((threadIdx.x & 63) == 0) ws4[threadIdx.x >> 6] = s;
    __syncthreads();
    if (threadIdx.x == 0) out[0] = (ws4[0]+ws4[1]+ws4[2]+ws4[3]) * (1.f/(float)(M_*CF_));
}

// ---------------------------------------------------------------------------
// Host
// ---------------------------------------------------------------------------
static constexpr size_t X_OFF     = 0;            // f32 x        25,165,824 B
static constexpr size_t H_OFF     = 25165824;     // bf16 h/xb    12,582,912 B
static constexpr size_t O_OFF     = 37748736;     // bf16 o/u/idx 12,582,912 B
static constexpr size_t QKV_OFF   = 50331648;     // bf16 q,k,v   37,748,736 B
static constexpr size_t WQKV_OFF  = 88080384;     // bf16         25,165,824 B
static constexpr size_t WPROJ_OFF = 113246208;    // bf16          8,388,608 B
static constexpr size_t W1_OFF    = 121634816;    // bf16          8,388,608 B
static constexpr size_t W2_OFF    = 130023424;    // bf16          8,388,608 B
static constexpr size_t WEMB_OFF  = 138412032;    // bf16            131,072 B
static constexpr size_t WFIN_OFF  = 138543104;    // bf16            131,072 B
static constexpr size_t PART_OFF  = 138674176;    // f32               4,096 B

extern "C" void kernel_launch(void* const* d_in, const int* in_sizes, int n_in,
                              void* d_out, int out_size, void* d_ws, size_t ws_size,
                              hipStream_t stream)
{
    const float* index   = (const float*)d_in[0];
    const float* targets = (const float*)d_in[1];
    const float* W_embed = (const float*)d_in[2];
    const float* b_embed = (const float*)d_in[3];
    const float* pe      = (const float*)d_in[4];
    const float* lpe     = (const float*)d_in[5];
    const float* Wq      = (const float*)d_in[6];
    const float* Wk      = (const float*)d_in[7];
    const float* Wv      = (const float*)d_in[8];
    const float* Wproj   = (const float*)d_in[9];
    const float* bproj   = (const float*)d_in[10];
    const float* ln1g    = (const float*)d_in[11];
    const float* ln1b    = (const float*)d_in[12];
    const float* ln2g    = (const float*)d_in[13];
    const float* ln2b    = (const float*)d_in[14];
    const float* W1      = (const float*)d_in[15];
    const float* b1      = (const float*)d_in[16];
    const float* W2      = (const float*)d_in[17];
    const float* b2      = (const float*)d_in[18];
    const float* Wfin    = (const float*)d_in[19];
    const float* bfin    = (const float*)d_in[20];

    char* ws = (char*)d_ws;
    float*          x     = (float*)(ws + X_OFF);
    unsigned short* hbuf  = (unsigned short*)(ws + H_OFF);
    unsigned short* obuf  = (unsigned short*)(ws + O_OFF);
    unsigned short* qkv   = (unsigned short*)(ws + QKV_OFF);
    unsigned short* wqkvp = (unsigned short*)(ws + WQKV_OFF);
    unsigned short* wprojp= (unsigned short*)(ws + WPROJ_OFF);
    unsigned short* w1p   = (unsigned short*)(ws + W1_OFF);
    unsigned short* w2p   = (unsigned short*)(ws + W2_OFF);
    unsigned short* wembp = (unsigned short*)(ws + WEMB_OFF);
    unsigned short* wfinp = (unsigned short*)(ws + WFIN_OFF);
    float*          part  = (float*)(ws + PART_OFF);
    float*          logits= (float*)d_out;

    // pack weights to bf16 B^T layouts
    pack_qkv_k<<<49152, 256, 0, stream>>>(Wq, Wk, Wv, wqkvp);
    pack_t_k<<<16384, 256, 0, stream>>>(Wproj, wprojp, 512, 512, 4194304);
    pack_t_k<<<16384, 256, 0, stream>>>(W1,    w1p,    512, 512, 4194304);
    pack_t_k<<<16384, 256, 0, stream>>>(W2,    w2p,    512, 512, 4194304);
    pack_t_k<<<256,   256, 0, stream>>>(W_embed, wembp, 128, 512, 65536);
    pack_t_k<<<256,   256, 0, stream>>>(Wfin,    wfinp, 512, 128, 65536);

    // embed: x = bf16(index) @ Wemb^T + b + pe + lpe
    cast4_k<<<1536, 256, 0, stream>>>(index, obuf, 393216);
    gemm_k<0><<<dim3(96,4), 256, 0, stream>>>(obuf, wembp, b_embed, pe, lpe, x, nullptr, 128);

    for (int l = 0; l < L_; ++l){
        ln_k<<<3072, 256, 0, stream>>>(x, ln1g + l*512, ln1b + l*512, hbuf);
        gemm_k<1><<<dim3(96,12), 256, 0, stream>>>(hbuf, wqkvp + (size_t)l*786432,
                                                   nullptr, nullptr, nullptr, nullptr, qkv, 512);
        attn_k<<<3072, 256, 0, stream>>>(qkv, qkv + 6291456, qkv + 2*6291456, obuf);
        gemm_k<2><<<dim3(96,4), 256, 0, stream>>>(obuf, wprojp + (size_t)l*262144,
                                                  bproj + l*512, nullptr, nullptr, x, nullptr, 512);
        ln_k<<<3072, 256, 0, stream>>>(x, ln2g + l*512, ln2b + l*512, hbuf);
        gemm_k<3><<<dim3(96,4), 256, 0, stream>>>(hbuf, w1p + (size_t)l*262144,
                                                  b1 + l*512, nullptr, nullptr, nullptr, obuf, 512);
        gemm_k<2><<<dim3(96,4), 256, 0, stream>>>(obuf, w2p + (size_t)l*262144,
                                                  b2 + l*512, nullptr, nullptr, x, nullptr, 512);
    }

    // final: logits = bf16(x) @ Wfin^T + b_final ; loss = mean((logits-targets)^2)
    cast4_k<<<6144, 256, 0, stream>>>(x, hbuf, 1572864);
    gemm_k<4><<<dim3(96,1), 256, 0, stream>>>(hbuf, wfinp, bfin, nullptr, nullptr, logits, nullptr, 512);
    loss1_k<<<1024, 256, 0, stream>>>(logits, targets, part);
    loss2_k<<<1, 256, 0, stream>>>(part, logits + 1572864);
}

// Round 4
// 2296.504 us; speedup vs baseline: 1.8206x; 1.0432x over previous
//
#include <hip/hip_runtime.h>
#include <hip/hip_bf16.h>

#define B_   32
#define T_   384
#define CF_  128
#define D_   512
#define H_   16
#define HD_  32
#define L_   16
#define HID_ 512
#define M_   (B_*T_)   // 12288

typedef __bf16 bf16x8 __attribute__((ext_vector_type(8)));
typedef float  f32x4  __attribute__((ext_vector_type(4)));

__device__ __forceinline__ float bf2f(unsigned short u){
    unsigned int x = ((unsigned int)u) << 16;
    return __builtin_bit_cast(float, x);
}
__device__ __forceinline__ unsigned short f2bf(float f){
    unsigned int u = __builtin_bit_cast(unsigned int, f);
    u += 0x7FFFu + ((u >> 16) & 1u);
    return (unsigned short)(u >> 16);
}

typedef const __attribute__((address_space(1))) unsigned int* gas_p;
typedef __attribute__((address_space(3))) unsigned int*       las_p;
__device__ __forceinline__ void gload16(const void* g, void* l){
    __builtin_amdgcn_global_load_lds((gas_p)g, (las_p)l, 16, 0, 0);
}

// ---------------------------------------------------------------------------
// Generic bf16 MFMA GEMM: C[M][N] = A[M][K] * Bt[N][K]^T  (Bt = B transposed)
// 128x128 tile, 256 threads (4 waves as 2x2 of 64x64), BK=32, double-buffered
// LDS staged via global_load_lds dwordx4 (linear LDS dest; XOR swizzle is
// applied to the global source slot, fragment reads unchanged).
// ---------------------------------------------------------------------------
template<int EPI>
__global__ __launch_bounds__(256) void gemm_k(
    const unsigned short* __restrict__ A,
    const unsigned short* __restrict__ Bt,
    const float* __restrict__ aux0,   // bias
    const float* __restrict__ aux1,   // pe
    const float* __restrict__ aux2,   // learnable pe
    float* __restrict__ fout,
    unsigned short* __restrict__ bout,
    int K)
{
    __shared__ unsigned short lA[2][128*32];
    __shared__ unsigned short lB[2][128*32];

    const int tid  = threadIdx.x;
    const int lane = tid & 63;
    const int w    = tid >> 6;
    const int wm   = w >> 1, wn = w & 1;
    const int li   = lane & 15, ls = lane >> 4;
    const int m0   = blockIdx.x * 128;
    const int n0   = blockIdx.y * 128;
    const int nkt  = K >> 5;

    // item e -> row r = e>>2, LDS slot q = e&3; global chunk s = q ^ swz(r)
    const int e0 = tid, e1 = tid + 256;
    const int r0 = e0 >> 2, s0 = (e0 & 3) ^ ((r0 >> 1) & 3);
    const int r1 = e1 >> 2, s1 = (e1 & 3) ^ ((r1 >> 1) & 3);
    const unsigned short* gA0 = A  + (size_t)(m0 + r0)*K + s0*8;
    const unsigned short* gA1 = A  + (size_t)(m0 + r1)*K + s1*8;
    const unsigned short* gB0 = Bt + (size_t)(n0 + r0)*K + s0*8;
    const unsigned short* gB1 = Bt + (size_t)(n0 + r1)*K + s1*8;

#define STAGE(c, kt) do{ \
    const int ko_ = (kt)*32; \
    gload16(gA0 + ko_, &lA[c][w*512]); \
    gload16(gA1 + ko_, &lA[c][2048 + w*512]); \
    gload16(gB0 + ko_, &lB[c][w*512]); \
    gload16(gB1 + ko_, &lB[c][2048 + w*512]); \
}while(0)

    f32x4 acc[4][4];
    #pragma unroll
    for (int i=0;i<4;i++)
        #pragma unroll
        for (int j=0;j<4;j++) acc[i][j] = (f32x4){0.f,0.f,0.f,0.f};

    STAGE(0, 0);
    asm volatile("s_waitcnt vmcnt(0)" ::: "memory");
    __syncthreads();

    int cur = 0;
    for (int kt = 0; kt < nkt; ++kt){
        if (kt + 1 < nkt) STAGE(cur^1, kt+1);
        bf16x8 af[4], bf[4];
        #pragma unroll
        for (int f=0; f<4; ++f){
            const int rA = wm*64 + f*16 + li;
            af[f] = *(const bf16x8*)&lA[cur][rA*32 + ((ls ^ ((rA>>1)&3))*8)];
            const int rB = wn*64 + f*16 + li;
            bf[f] = *(const bf16x8*)&lB[cur][rB*32 + ((ls ^ ((rB>>1)&3))*8)];
        }
        #pragma unroll
        for (int i=0;i<4;i++)
            #pragma unroll
            for (int j=0;j<4;j++)
                acc[i][j] = __builtin_amdgcn_mfma_f32_16x16x32_bf16(af[i], bf[j], acc[i][j], 0, 0, 0);
        __syncthreads();
        cur ^= 1;
    }
#undef STAGE

    // epilogue: D layout col = lane&15, row = (lane>>4)*4 + t  (verified m89)
    #pragma unroll
    for (int i=0;i<4;i++){
        #pragma unroll
        for (int j=0;j<4;j++){
            #pragma unroll
            for (int t=0;t<4;t++){
                const int row = m0 + wm*64 + i*16 + ls*4 + t;
                const int col = n0 + wn*64 + j*16 + li;
                const float v = acc[i][j][t];
                if constexpr (EPI == 0){
                    const int tt = row % T_;
                    fout[row*D_ + col] = v + aux0[col] + aux1[tt*D_ + col] + aux2[tt*D_ + col];
                } else if constexpr (EPI == 1){
                    const int mat = col >> 9, nl = col & 511;
                    const int hh = nl >> 5, dd = nl & 31;
                    const int bb = row / T_, tt = row % T_;
                    bout[mat*(M_*D_) + (((bb*H_ + hh)*T_ + tt)*HD_) + dd] = f2bf(v);
                } else if constexpr (EPI == 2){
                    fout[row*D_ + col] += v + aux0[col];
                } else if constexpr (EPI == 3){
                    const float r = v + aux0[col];
                    bout[row*HID_ + col] = f2bf(r > 0.f ? r : 0.f);
                } else {
                    fout[row*CF_ + col] = v + aux0[col];
                }
            }
        }
    }
}

// ---------------------------------------------------------------------------
// LayerNorm: one wave per row of 512, out bf16
// ---------------------------------------------------------------------------
__global__ __launch_bounds__(256) void ln_k(const float* __restrict__ x,
                                            const float* __restrict__ g,
                                            const float* __restrict__ b,
                                            unsigned short* __restrict__ out)
{
    const int w = threadIdx.x >> 6, lane = threadIdx.x & 63;
    const int row = blockIdx.x*4 + w;
    const float* xr = x + (size_t)row*D_;
    const float4 a = *(const float4*)(xr + lane*8);
    const float4 c = *(const float4*)(xr + lane*8 + 4);
    float s  = a.x+a.y+a.z+a.w + c.x+c.y+c.z+c.w;
    float q2 = a.x*a.x+a.y*a.y+a.z*a.z+a.w*a.w + c.x*c.x+c.y*c.y+c.z*c.z+c.w*c.w;
    #pragma unroll
    for (int off=32; off; off>>=1){
        s  += __shfl_xor(s,  off);
        q2 += __shfl_xor(q2, off);
    }
    const float mean = s * (1.f/512.f);
    const float var  = q2 * (1.f/512.f) - mean*mean;
    const float rstd = rsqrtf(var + 1e-6f);
    const float4 gA = *(const float4*)(g + lane*8);
    const float4 gB = *(const float4*)(g + lane*8 + 4);
    const float4 bA = *(const float4*)(b + lane*8);
    const float4 bB = *(const float4*)(b + lane*8 + 4);
    alignas(16) unsigned short o8[8];
    o8[0] = f2bf((a.x-mean)*rstd*gA.x + bA.x);
    o8[1] = f2bf((a.y-mean)*rstd*gA.y + bA.y);
    o8[2] = f2bf((a.z-mean)*rstd*gA.z + bA.z);
    o8[3] = f2bf((a.w-mean)*rstd*gA.w + bA.w);
    o8[4] = f2bf((c.x-mean)*rstd*gB.x + bB.x);
    o8[5] = f2bf((c.y-mean)*rstd*gB.y + bB.y);
    o8[6] = f2bf((c.z-mean)*rstd*gB.z + bB.z);
    o8[7] = f2bf((c.w-mean)*rstd*gB.w + bB.w);
    *(uint4*)(out + (size_t)row*D_ + lane*8) = *(const uint4*)o8;
}

// ---------------------------------------------------------------------------
// Causal flash attention, scale = 1/sqrt(512). q,k,v: [BH][T][32] bf16.
// 1-D grid (3072), XCD-chunk swizzled. Online softmax in registers,
// P transposed through a tiny per-wave LDS scratch.
// ---------------------------------------------------------------------------
__global__ __launch_bounds__(256) void attn_k(const unsigned short* __restrict__ q,
                                              const unsigned short* __restrict__ k,
                                              const unsigned short* __restrict__ v,
                                              unsigned short* __restrict__ o)
{
    constexpr int VSTR = 408;                    // dword stride 204 = 12 mod 32
    __shared__ unsigned short Vt[32][VSTR];      // 26,112 B
    __shared__ unsigned short Pb[4][16*40];      //  5,120 B (per-wave 16x32, stride 40)

    // bijective XCD-chunk swizzle: 3072 = 8 XCDs * 384
    const int orig = blockIdx.x;
    const int wg   = (orig & 7)*384 + (orig >> 3);
    const int bh   = wg / 6;
    const int t0   = (wg - bh*6) * 64;

    const int tid = threadIdx.x;
    const int lane = tid & 63, w = tid >> 6;
    const int li = lane & 15, ls = lane >> 4;
    const unsigned short* qb = q + (size_t)bh*(T_*HD_);
    const unsigned short* kb = k + (size_t)bh*(T_*HD_);
    const unsigned short* vb = v + (size_t)bh*(T_*HD_);

    // --- stage V transposed (causal range only), coalesced reads ---
    const int nS = t0 + 64;
    const int items = (nS >> 1) * 4;            // (s-pairs) x (4 chunks of 8 d)
    for (int it = tid; it < items; it += 256){
        const int p  = it >> 2;
        const int d0 = (it & 3) << 3;
        const int s  = p << 1;
        const uint4 va0 = *(const uint4*)(vb + s*HD_ + d0);
        const uint4 va1 = *(const uint4*)(vb + (s+1)*HD_ + d0);
        const unsigned short* a16 = (const unsigned short*)&va0;
        const unsigned short* b16 = (const unsigned short*)&va1;
        #pragma unroll
        for (int j=0;j<8;j++)
            *(unsigned int*)&Vt[d0+j][s] = (unsigned int)a16[j] | ((unsigned int)b16[j] << 16);
    }

    const int trow0 = t0 + w*16;                // wave's first q row
    const int rowg  = trow0 + ls*4;             // lane's first accumulated row
    const bf16x8 qa = *(const bf16x8*)(qb + (trow0 + li)*HD_ + ls*8);
    const float scale = 0.04419417382415922f;   // 1/sqrt(512)
    const int nc = (trow0 + 16 + 31) >> 5;      // 32-wide k-chunks

    f32x4 m4 = {-1e30f,-1e30f,-1e30f,-1e30f};
    f32x4 l4 = {0.f,0.f,0.f,0.f};
    f32x4 oa0 = {0.f,0.f,0.f,0.f}, oa1 = {0.f,0.f,0.f,0.f};
    unsigned short* pw = Pb[w];

    __syncthreads();                            // Vt ready

    bf16x8 kf0 = *(const bf16x8*)(kb + (li)*HD_ + ls*8);
    bf16x8 kf1 = *(const bf16x8*)(kb + (16 + li)*HD_ + ls*8);

    for (int c = 0; c < nc; ++c){
        // QK^T (scores in regs: row = ls*4+j, col = c*32 + li (+16))
        f32x4 s0 = {0.f,0.f,0.f,0.f}, s1 = {0.f,0.f,0.f,0.f};
        s0 = __builtin_amdgcn_mfma_f32_16x16x32_bf16(qa, kf0, s0, 0, 0, 0);
        s1 = __builtin_amdgcn_mfma_f32_16x16x32_bf16(qa, kf1, s1, 0, 0, 0);
        if (c + 1 < nc){
            kf0 = *(const bf16x8*)(kb + ((c+1)*32 + li)*HD_ + ls*8);
            kf1 = *(const bf16x8*)(kb + ((c+1)*32 + 16 + li)*HD_ + ls*8);
        }

        const int colg0 = c*32 + li;
        const int colg1 = colg0 + 16;
        float p0[4], p1[4];
        #pragma unroll
        for (int j=0;j<4;j++){
            const int rg = rowg + j;
            float v0 = (colg0 <= rg) ? s0[j]*scale : -1e30f;
            float v1 = (colg1 <= rg) ? s1[j]*scale : -1e30f;
            // chunk row-max across the 16 li lanes
            float cm = fmaxf(v0, v1);
            cm = fmaxf(cm, __shfl_xor(cm, 1));
            cm = fmaxf(cm, __shfl_xor(cm, 2));
            cm = fmaxf(cm, __shfl_xor(cm, 4));
            cm = fmaxf(cm, __shfl_xor(cm, 8));
            const float mo = m4[j];
            const float mn = fmaxf(mo, cm);
            const float f  = __expf(mo - mn);   // 0 when mo = -1e30
            m4[j] = mn;
            const float e0 = __expf(v0 - mn);
            const float e1 = __expf(v1 - mn);
            l4[j]  = l4[j]*f + e0 + e1;         // per-lane partial row sum
            oa0[j] *= f;  oa1[j] *= f;
            p0[j] = e0;   p1[j] = e1;
        }

        // transpose P (16x32) through per-wave LDS scratch
        #pragma unroll
        for (int j=0;j<4;j++){
            pw[(ls*4+j)*40 + li]      = f2bf(p0[j]);
            pw[(ls*4+j)*40 + 16 + li] = f2bf(p1[j]);
        }
        asm volatile("s_waitcnt lgkmcnt(0)" ::: "memory");
        const bf16x8 pa  = *(const bf16x8*)&pw[li*40 + ls*8];
        const bf16x8 vf0 = *(const bf16x8*)&Vt[li][c*32 + ls*8];
        const bf16x8 vf1 = *(const bf16x8*)&Vt[16 + li][c*32 + ls*8];
        oa0 = __builtin_amdgcn_mfma_f32_16x16x32_bf16(pa, vf0, oa0, 0, 0, 0);
        oa1 = __builtin_amdgcn_mfma_f32_16x16x32_bf16(pa, vf1, oa1, 0, 0, 0);
    }

    // finalize row sums (reduce per-lane partials across li)
    #pragma unroll
    for (int j=0;j<4;j++){
        float s = l4[j];
        s += __shfl_xor(s, 1);
        s += __shfl_xor(s, 2);
        s += __shfl_xor(s, 4);
        s += __shfl_xor(s, 8);
        l4[j] = s;
    }

    const int bb = bh >> 4, hh = bh & 15;
    #pragma unroll
    for (int j=0;j<4;j++){
        const int tg = trow0 + ls*4 + j;
        const float inv = 1.f / l4[j];
        o[(size_t)(bb*T_ + tg)*D_ + hh*HD_ + li]      = f2bf(oa0[j]*inv);
        o[(size_t)(bb*T_ + tg)*D_ + hh*HD_ + 16 + li] = f2bf(oa1[j]*inv);
    }
}

// ---------------------------------------------------------------------------
// Coalesced tiled transpose packs (f32 -> bf16)
// packT_k: per batch z, src[R][C] f32 -> dst[C][R] bf16. grid(C/64, R/64, Z)
// ---------------------------------------------------------------------------
__global__ __launch_bounds__(256) void packT_k(const float* __restrict__ src,
                                               unsigned short* __restrict__ dst,
                                               int R, int C)
{
    __shared__ unsigned short tile[64][72];      // [c][r], row base 144B (16B-aligned)
    const int z  = blockIdx.z;
    const float* s = src + (size_t)z*R*C;
    unsigned short* d = dst + (size_t)z*R*C;
    const int c0 = blockIdx.x*64, r0 = blockIdx.y*64;

    for (int it = threadIdx.x; it < 1024; it += 256){
        const int rr  = it >> 4;
        const int cc4 = (it & 15) << 2;
        const float4 v = *(const float4*)(s + (size_t)(r0+rr)*C + c0 + cc4);
        tile[cc4  ][rr] = f2bf(v.x);
        tile[cc4+1][rr] = f2bf(v.y);
        tile[cc4+2][rr] = f2bf(v.z);
        tile[cc4+3][rr] = f2bf(v.w);
    }
    __syncthreads();
    for (int it = threadIdx.x; it < 512; it += 256){
        const int cc = it >> 3;
        const int ch = (it & 7) << 3;
        *(uint4*)(d + (size_t)(c0+cc)*R + r0 + ch) = *(const uint4*)&tile[cc][ch];
    }
}

// pack_qkv: Wq/Wk/Wv [l][h][512][32] f32 -> dst[(l*3+mat)*512x512 panel][n=h*32+dd][kk]
// grid(4 kk-chunks, 48 = mat*16+h, 16 l)
__global__ __launch_bounds__(256) void pack_qkv_k(const float* __restrict__ Wq,
                                                  const float* __restrict__ Wk,
                                                  const float* __restrict__ Wv,
                                                  unsigned short* __restrict__ dst)
{
    __shared__ unsigned short tile[32][136];     // [dd][kk], row base 272B
    const int kc  = blockIdx.x;                  // 128-row kk chunk
    const int mat = blockIdx.y >> 4;
    const int h   = blockIdx.y & 15;
    const int l   = blockIdx.z;
    const float* src = ((mat==0) ? Wq : (mat==1) ? Wk : Wv)
                     + ((size_t)(l*H_ + h)*D_ + kc*128)*HD_;

    for (int it = threadIdx.x; it < 1024; it += 256){
        const int rr  = it >> 3;                 // kk within chunk, 0..127
        const int dd4 = (it & 7) << 2;
        const float4 v = *(const float4*)(src + (size_t)rr*HD_ + dd4);
        tile[dd4  ][rr] = f2bf(v.x);
        tile[dd4+1][rr] = f2bf(v.y);
        tile[dd4+2][rr] = f2bf(v.z);
        tile[dd4+3][rr] = f2bf(v.w);
    }
    __syncthreads();
    unsigned short* dp = dst + (size_t)l*786432 + (size_t)mat*262144 + kc*128;
    for (int it = threadIdx.x; it < 512; it += 256){
        const int dd = it >> 4;
        const int ch = (it & 15) << 3;
        *(uint4*)(dp + (size_t)(h*32 + dd)*512 + ch) = *(const uint4*)&tile[dd][ch];
    }
}

__global__ void cast4_k(const float* __restrict__ src, unsigned short* __restrict__ dst, int total4)
{
    const int i = blockIdx.x*256 + threadIdx.x;
    if (i >= total4) return;
    const float4 vv = ((const float4*)src)[i];
    alignas(8) unsigned short t[4] = { f2bf(vv.x), f2bf(vv.y), f2bf(vv.z), f2bf(vv.w) };
    *(uint2*)(dst + (size_t)i*4) = *(const uint2*)t;
}

__global__ __launch_bounds__(256) void loss1_k(const float* __restrict__ logits,
                                               const float* __restrict__ tgt,
                                               float* __restrict__ part)
{
    float s = 0.f;
    for (int i = blockIdx.x*256 + threadIdx.x; i < M_*CF_; i += 256*1024){
        const float d = logits[i] - tgt[i];
        s += d*d;
    }
    #pragma unroll
    for (int off=32; off; off>>=1) s += __shfl_xor(s, off);
    __shared__ float ws4[4];
    if ((threadIdx.x & 63) == 0) ws4[threadIdx.x >> 6] = s;
    __syncthreads();
    if (threadIdx.x == 0) part[blockIdx.x] = ws4[0]+ws4[1]+ws4[2]+ws4[3];
}

__global__ __launch_bounds__(256) void loss2_k(const float* __restrict__ part,
                                               float* __restrict__ out)
{
    float s = 0.f;
    for (int i = threadIdx.x; i < 1024; i += 256) s += part[i];
    #pragma unroll
    for (int off=32; off; off>>=1) s += __shfl_xor(s, off);
    __shared__ float ws4[4];
    if ((threadIdx.x & 63) == 0) ws4[threadIdx.x >> 6] = s;
    __syncthreads();
    if (threadIdx.x == 0) out[0] = (ws4[0]+ws4[1]+ws4[2]+ws4[3]) * (1.f/(float)(M_*CF_));
}

// ---------------------------------------------------------------------------
// Host
// ---------------------------------------------------------------------------
static constexpr size_t X_OFF     = 0;            // f32 x        25,165,824 B
static constexpr size_t H_OFF     = 25165824;     // bf16 h/xb    12,582,912 B
static constexpr size_t O_OFF     = 37748736;     // bf16 o/u/idx 12,582,912 B
static constexpr size_t QKV_OFF   = 50331648;     // bf16 q,k,v   37,748,736 B
static constexpr size_t WQKV_OFF  = 88080384;     // bf16         25,165,824 B
static constexpr size_t WPROJ_OFF = 113246208;    // bf16          8,388,608 B
static constexpr size_t W1_OFF    = 121634816;    // bf16          8,388,608 B
static constexpr size_t W2_OFF    = 130023424;    // bf16          8,388,608 B
static constexpr size_t WEMB_OFF  = 138412032;    // bf16            131,072 B
static constexpr size_t WFIN_OFF  = 138543104;    // bf16            131,072 B
static constexpr size_t PART_OFF  = 138674176;    // f32               4,096 B

extern "C" void kernel_launch(void* const* d_in, const int* in_sizes, int n_in,
                              void* d_out, int out_size, void* d_ws, size_t ws_size,
                              hipStream_t stream)
{
    const float* index   = (const float*)d_in[0];
    const float* targets = (const float*)d_in[1];
    const float* W_embed = (const float*)d_in[2];
    const float* b_embed = (const float*)d_in[3];
    const float* pe      = (const float*)d_in[4];
    const float* lpe     = (const float*)d_in[5];
    const float* Wq      = (const float*)d_in[6];
    const float* Wk      = (const float*)d_in[7];
    const float* Wv      = (const float*)d_in[8];
    const float* Wproj   = (const float*)d_in[9];
    const float* bproj   = (const float*)d_in[10];
    const float* ln1g    = (const float*)d_in[11];
    const float* ln1b    = (const float*)d_in[12];
    const float* ln2g    = (const float*)d_in[13];
    const float* ln2b    = (const float*)d_in[14];
    const float* W1      = (const float*)d_in[15];
    const float* b1      = (const float*)d_in[16];
    const float* W2      = (const float*)d_in[17];
    const float* b2      = (const float*)d_in[18];
    const float* Wfin    = (const float*)d_in[19];
    const float* bfin    = (const float*)d_in[20];

    char* ws = (char*)d_ws;
    float*          x     = (float*)(ws + X_OFF);
    unsigned short* hbuf  = (unsigned short*)(ws + H_OFF);
    unsigned short* obuf  = (unsigned short*)(ws + O_OFF);
    unsigned short* qkv   = (unsigned short*)(ws + QKV_OFF);
    unsigned short* wqkvp = (unsigned short*)(ws + WQKV_OFF);
    unsigned short* wprojp= (unsigned short*)(ws + WPROJ_OFF);
    unsigned short* w1p   = (unsigned short*)(ws + W1_OFF);
    unsigned short* w2p   = (unsigned short*)(ws + W2_OFF);
    unsigned short* wembp = (unsigned short*)(ws + WEMB_OFF);
    unsigned short* wfinp = (unsigned short*)(ws + WFIN_OFF);
    float*          part  = (float*)(ws + PART_OFF);
    float*          logits= (float*)d_out;

    // pack weights to bf16 B^T layouts (coalesced LDS-transpose)
    pack_qkv_k<<<dim3(4,48,16), 256, 0, stream>>>(Wq, Wk, Wv, wqkvp);
    packT_k<<<dim3(8,8,16), 256, 0, stream>>>(Wproj, wprojp, 512, 512);
    packT_k<<<dim3(8,8,16), 256, 0, stream>>>(W1,    w1p,    512, 512);
    packT_k<<<dim3(8,8,16), 256, 0, stream>>>(W2,    w2p,    512, 512);
    packT_k<<<dim3(8,2,1),  256, 0, stream>>>(W_embed, wembp, 128, 512);
    packT_k<<<dim3(2,8,1),  256, 0, stream>>>(Wfin,    wfinp, 512, 128);

    // embed: x = bf16(index) @ Wemb^T + b + pe + lpe
    cast4_k<<<1536, 256, 0, stream>>>(index, obuf, 393216);
    gemm_k<0><<<dim3(96,4), 256, 0, stream>>>(obuf, wembp, b_embed, pe, lpe, x, nullptr, 128);

    for (int l = 0; l < L_; ++l){
        ln_k<<<3072, 256, 0, stream>>>(x, ln1g + l*512, ln1b + l*512, hbuf);
        gemm_k<1><<<dim3(96,12), 256, 0, stream>>>(hbuf, wqkvp + (size_t)l*786432,
                                                   nullptr, nullptr, nullptr, nullptr, qkv, 512);
        attn_k<<<3072, 256, 0, stream>>>(qkv, qkv + 6291456, qkv + 2*6291456, obuf);
        gemm_k<2><<<dim3(96,4), 256, 0, stream>>>(obuf, wprojp + (size_t)l*262144,
                                                  bproj + l*512, nullptr, nullptr, x, nullptr, 512);
        ln_k<<<3072, 256, 0, stream>>>(x, ln2g + l*512, ln2b + l*512, hbuf);
        gemm_k<3><<<dim3(96,4), 256, 0, stream>>>(hbuf, w1p + (size_t)l*262144,
                                                  b1 + l*512, nullptr, nullptr, nullptr, obuf, 512);
        gemm_k<2><<<dim3(96,4), 256, 0, stream>>>(obuf, w2p + (size_t)l*262144,
                                                  b2 + l*512, nullptr, nullptr, x, nullptr, 512);
    }

    // final: logits = bf16(x) @ Wfin^T + b_final ; loss = mean((logits-targets)^2)
    cast4_k<<<6144, 256, 0, stream>>>(x, hbuf, 1572864);
    gemm_k<4><<<dim3(96,1), 256, 0, stream>>>(hbuf, wfinp, bfin, nullptr, nullptr, logits, nullptr, 512);
    loss1_k<<<1024, 256, 0, stream>>>(logits, targets, part);
    loss2_k<<<1, 256, 0, stream>>>(part, logits + 1572864);
}